// Round 1
// baseline (221.901 us; speedup 1.0000x reference)
//
#include <hip/hip_runtime.h>
#include <math.h>

#define NB 256
#define NF 8
#define NS 200
#define ND 64
#define NH 36
#define MT 13              // 13 m-tiles of 16 rows cover 208 >= 200
#define EPSV 1e-3f

// ws float-offset layout:
#define WS_SUM 0                          // [0,288)    per-(f,h) sum
#define WS_SQ  288                        // [288,576)  per-(f,h) sumsq
#define WS_QT  1152                       // 2048*48 floats: qt[b,f,h] (h padded to 48)
#define WS_WK  (1152 + 2048 * 48)         // bf16 WkT[f][h(48)][d(64)] = (W1-W3)^T, 8*48*64 shorts
#define WS_W23 (WS_WK + (NF * 48 * ND) / 2)  // f32 W23[f][d(64)][h(48)] = W2+W3

typedef __attribute__((ext_vector_type(8))) short short8;
typedef __attribute__((ext_vector_type(4))) float f32x4;

__device__ __forceinline__ unsigned short f32_to_bf16(float x) {
    unsigned u = __float_as_uint(x);
    unsigned r = u + 0x7FFFu + ((u >> 16) & 1u);   // round-to-nearest-even
    return (unsigned short)(r >> 16);
}
__device__ __forceinline__ short8 cvt8(float4 a, float4 b) {
    short8 r;
    r[0] = (short)f32_to_bf16(a.x); r[1] = (short)f32_to_bf16(a.y);
    r[2] = (short)f32_to_bf16(a.z); r[3] = (short)f32_to_bf16(a.w);
    r[4] = (short)f32_to_bf16(b.x); r[5] = (short)f32_to_bf16(b.y);
    r[6] = (short)f32_to_bf16(b.z); r[7] = (short)f32_to_bf16(b.w);
    return r;
}

// blocks 0..7: per-f weight prep (WkT bf16, W23 f32). block 8: zero stats accumulators.
__global__ __launch_bounds__(256) void k_prep(
    const float* __restrict__ W_h, float* __restrict__ ws)
{
    const int blk = blockIdx.x, tid = threadIdx.x;
    if (blk < NF) {
        const int f = blk;
        const float* Wf = W_h + (size_t)f * (3 * ND * NH);
        unsigned short* wk = (unsigned short*)(ws + WS_WK) + f * (48 * ND);
        for (int i = tid; i < 48 * ND; i += 256) {
            int h = i >> 6, d = i & 63;
            float v = (h < NH) ? (Wf[d * NH + h] - Wf[(2 * ND + d) * NH + h]) : 0.f;
            wk[h * ND + d] = f32_to_bf16(v);
        }
        float* w23 = ws + WS_W23 + f * (ND * 48);
        for (int i = tid; i < ND * 48; i += 256) {
            int d = i / 48, h = i - d * 48;
            w23[i] = (h < NH) ? (Wf[(ND + d) * NH + h] + Wf[(2 * ND + d) * NH + h]) : 0.f;
        }
    } else {
        for (int i = tid; i < 576; i += 256) ws[i] = 0.f;
    }
}

__global__ __launch_bounds__(256, 4) void k_stats(
    const float* __restrict__ query, const float* __restrict__ key,
    const float* __restrict__ b_h, float* __restrict__ ws)
{
    const int blk = blockIdx.x;           // = b*NF + f
    const int f = blk & (NF - 1);
    const int tid = threadIdx.x;
    const int lane = tid & 63;
    const int wv = tid >> 6;
    const int col = lane & 15;
    const int quad = lane >> 4;

    __shared__ float sumP[48], sqP[48];
    __shared__ float qsh[ND];
    __shared__ float qt_sh[48];
    if (tid < 48) { sumP[tid] = 0.f; sqP[tid] = 0.f; }
    if (tid < ND) qsh[tid] = query[(size_t)blk * ND + tid];
    __syncthreads();

    // qt[h] = b_h[f,h] + q . (W2+W3)[:,h]   (f32, W23 is L2-hot)
    if (tid < 48) {
        const int h = tid;
        float acc = (h < NH) ? b_h[f * NH + h] : 0.f;
        const float* w23 = ws + WS_W23 + f * (ND * 48);
        #pragma unroll 8
        for (int d = 0; d < ND; ++d) acc += qsh[d] * w23[d * 48 + h];
        qt_sh[h] = acc;
        ws[WS_QT + (size_t)blk * 48 + h] = acc;   // reused by k_attn
    }
    __syncthreads();

    const float* kbase = key + (size_t)blk * (NS * ND);
    const unsigned short* wk = (const unsigned short*)(ws + WS_WK) + f * (48 * ND);

    short8 bfr[3][2];
    float qv[3];
    #pragma unroll
    for (int nt = 0; nt < 3; ++nt) {
        #pragma unroll
        for (int ks = 0; ks < 2; ++ks)
            bfr[nt][ks] = *(const short8*)&wk[(nt * 16 + col) * ND + ks * 32 + quad * 8];
        qv[nt] = qt_sh[nt * 16 + col];
    }

    float s_sum[3] = {0.f, 0.f, 0.f}, s_sq[3] = {0.f, 0.f, 0.f};
    for (int mt = wv; mt < MT; mt += 4) {
        const int s = 16 * mt + col;
        const float4* p = (const float4*)(kbase + (size_t)(s < NS ? s : NS - 1) * ND + quad * 8);
        float4 a0 = p[0], a1 = p[1];      // d = quad*8 .. +7
        float4 b0 = p[8], b1 = p[9];      // d = 32+quad*8 .. +7
        short8 ah0 = cvt8(a0, a1);
        short8 ah1 = cvt8(b0, b1);
        #pragma unroll
        for (int nt = 0; nt < 3; ++nt) {
            f32x4 acc = {qv[nt], qv[nt], qv[nt], qv[nt]};
            acc = __builtin_amdgcn_mfma_f32_16x16x32_bf16(ah0, bfr[nt][0], acc, 0, 0, 0);
            acc = __builtin_amdgcn_mfma_f32_16x16x32_bf16(ah1, bfr[nt][1], acc, 0, 0, 0);
            #pragma unroll
            for (int r = 0; r < 4; ++r) {
                int srow = 16 * mt + quad * 4 + r;
                if (srow < NS) { float v = acc[r]; s_sum[nt] += v; s_sq[nt] += v * v; }
            }
        }
    }
    #pragma unroll
    for (int nt = 0; nt < 3; ++nt) {
        float sv = s_sum[nt], qq = s_sq[nt];
        sv += __shfl_xor(sv, 16, 64); sv += __shfl_xor(sv, 32, 64);
        qq += __shfl_xor(qq, 16, 64); qq += __shfl_xor(qq, 32, 64);
        if (quad == 0) {
            atomicAdd(&sumP[nt * 16 + col], sv);
            atomicAdd(&sqP[nt * 16 + col], qq);
        }
    }
    __syncthreads();
    if (tid < NH) {
        atomicAdd(&ws[WS_SUM + f * NH + tid], sumP[tid]);
        atomicAdd(&ws[WS_SQ + f * NH + tid], sqP[tid]);
    }
}

__global__ __launch_bounds__(256, 4) void k_attn(
    const float* __restrict__ key, const float* __restrict__ alpha,
    const float* __restrict__ W_o, const float* __restrict__ b_o,
    const int* __restrict__ seqn, const float* __restrict__ ws,
    float* __restrict__ out)
{
    const int blk = blockIdx.x;           // = b*NF + f
    const int f = blk & (NF - 1);
    const int tid = threadIdx.x;
    const int lane = tid & 63;
    const int wv = tid >> 6;
    const int col = lane & 15;
    const int quad = lane >> 4;

    __shared__ float sw[208];             // scores, then softmax weights
    __shared__ float redM[4], redS[4];
    __shared__ float pout[4][64];

    const float* kbase = key + (size_t)blk * (NS * ND);
    const unsigned short* wk = (const unsigned short*)(ws + WS_WK) + f * (48 * ND);
    const float inv_n = 1.f / (float)(NB * NS);

    short8 bfr[3][2];
    float qv[3], mn[3], iv[3], wo[3];
    #pragma unroll
    for (int nt = 0; nt < 3; ++nt) {
        #pragma unroll
        for (int ks = 0; ks < 2; ++ks)
            bfr[nt][ks] = *(const short8*)&wk[(nt * 16 + col) * ND + ks * 32 + quad * 8];
        const int hh = nt * 16 + col;
        const bool hv = hh < NH;
        const int hc = hv ? hh : 0;
        qv[nt] = ws[WS_QT + (size_t)blk * 48 + hh];
        const float sm = ws[WS_SUM + f * NH + hc];
        const float sq = ws[WS_SQ + f * NH + hc];
        const float m = sm * inv_n;
        mn[nt] = m;
        iv[nt] = rsqrtf(fmaxf(sq * inv_n - m * m, 0.f) + EPSV);
        wo[nt] = hv ? W_o[f * NH + hh] : 0.f;
    }
    const float alf = alpha[f];
    const float bo = b_o[f];
    const int sq_n = seqn[blk];

    // score phase: h via MFMA, gated sum to scores (no register retention of key)
    #pragma unroll
    for (int t = 0; t < 4; ++t) {
        const int mt = wv + 4 * t;
        if (mt < MT) {
            const int s = 16 * mt + col;
            const float4* p = (const float4*)(kbase + (size_t)(s < NS ? s : NS - 1) * ND + quad * 8);
            float4 a0 = p[0], a1 = p[1];
            float4 b0 = p[8], b1 = p[9];
            short8 ah0 = cvt8(a0, a1);
            short8 ah1 = cvt8(b0, b1);
            float part[4] = {0.f, 0.f, 0.f, 0.f};
            #pragma unroll
            for (int nt = 0; nt < 3; ++nt) {
                f32x4 acc = {qv[nt], qv[nt], qv[nt], qv[nt]};
                acc = __builtin_amdgcn_mfma_f32_16x16x32_bf16(ah0, bfr[nt][0], acc, 0, 0, 0);
                acc = __builtin_amdgcn_mfma_f32_16x16x32_bf16(ah1, bfr[nt][1], acc, 0, 0, 0);
                #pragma unroll
                for (int r = 0; r < 4; ++r) {
                    const float h = acc[r];
                    const float pg = 1.f / (1.f + __expf(-(h - mn[nt]) * iv[nt]));
                    part[r] += (alf + (1.f - alf) * pg) * h * wo[nt];
                }
            }
            #pragma unroll
            for (int r = 0; r < 4; ++r) {
                float v = part[r];
                v += __shfl_xor(v, 1, 64);
                v += __shfl_xor(v, 2, 64);
                v += __shfl_xor(v, 4, 64);
                v += __shfl_xor(v, 8, 64);
                const int srow = 16 * mt + quad * 4 + r;
                if (col == 0 && srow < NS) sw[srow] = v + bo;
            }
        }
    }
    __syncthreads();

    // softmax over s
    const bool valid = (tid < 208) && (tid < sq_n);
    const float sc = valid ? sw[tid] : -1e30f;
    float m = sc;
    m = fmaxf(m, __shfl_xor(m, 1, 64));  m = fmaxf(m, __shfl_xor(m, 2, 64));
    m = fmaxf(m, __shfl_xor(m, 4, 64));  m = fmaxf(m, __shfl_xor(m, 8, 64));
    m = fmaxf(m, __shfl_xor(m, 16, 64)); m = fmaxf(m, __shfl_xor(m, 32, 64));
    if (lane == 0) redM[wv] = m;
    __syncthreads();
    const float maxv = fmaxf(fmaxf(redM[0], redM[1]), fmaxf(redM[2], redM[3]));
    const float e = valid ? __expf(sc - maxv) : 0.f;
    float l = e;
    l += __shfl_xor(l, 1, 64);  l += __shfl_xor(l, 2, 64);
    l += __shfl_xor(l, 4, 64);  l += __shfl_xor(l, 8, 64);
    l += __shfl_xor(l, 16, 64); l += __shfl_xor(l, 32, 64);
    if (lane == 0) redS[wv] = l;
    __syncthreads();
    const float isum = 1.f / (redS[0] + redS[1] + redS[2] + redS[3]);
    if (tid < 208) sw[tid] = e * isum;
    __syncthreads();

    // out = attn @ key; key re-read f32 from L2/L3 (slice is hot from score phase)
    float po0[8] = {0,0,0,0,0,0,0,0}, po1[8] = {0,0,0,0,0,0,0,0};
    #pragma unroll
    for (int t = 0; t < 4; ++t) {
        const int mt = wv + 4 * t;
        if (mt < MT) {
            const int s = 16 * mt + col;
            const float w = sw[16 * mt + col];   // rows >= NS carry weight 0
            const float4* p = (const float4*)(kbase + (size_t)(s < NS ? s : NS - 1) * ND + quad * 8);
            float4 a0 = p[0], a1 = p[1];
            float4 b0 = p[8], b1 = p[9];
            po0[0] += w * a0.x; po0[1] += w * a0.y; po0[2] += w * a0.z; po0[3] += w * a0.w;
            po0[4] += w * a1.x; po0[5] += w * a1.y; po0[6] += w * a1.z; po0[7] += w * a1.w;
            po1[0] += w * b0.x; po1[1] += w * b0.y; po1[2] += w * b0.z; po1[3] += w * b0.w;
            po1[4] += w * b1.x; po1[5] += w * b1.y; po1[6] += w * b1.z; po1[7] += w * b1.w;
        }
    }
    #pragma unroll
    for (int off = 1; off <= 8; off <<= 1) {
        #pragma unroll
        for (int j = 0; j < 8; ++j) {
            po0[j] += __shfl_xor(po0[j], off, 64);
            po1[j] += __shfl_xor(po1[j], off, 64);
        }
    }
    if (col == 0) {
        #pragma unroll
        for (int j = 0; j < 8; ++j) {
            pout[wv][quad * 8 + j] = po0[j];
            pout[wv][32 + quad * 8 + j] = po1[j];
        }
    }
    __syncthreads();
    if (tid < 64)
        out[(size_t)blk * ND + tid] =
            pout[0][tid] + pout[1][tid] + pout[2][tid] + pout[3][tid];
}

extern "C" void kernel_launch(void* const* d_in, const int* in_sizes, int n_in,
                              void* d_out, int out_size, void* d_ws, size_t ws_size,
                              hipStream_t stream) {
    const float* query = (const float*)d_in[0];
    const float* key   = (const float*)d_in[1];
    const float* W_h   = (const float*)d_in[2];
    const float* b_h   = (const float*)d_in[3];
    const float* alpha = (const float*)d_in[4];
    const float* W_o   = (const float*)d_in[5];
    const float* b_o   = (const float*)d_in[6];
    const int*   seqn  = (const int*)d_in[7];
    float* out = (float*)d_out;
    float* ws  = (float*)d_ws;

    k_prep<<<NF + 1, 256, 0, stream>>>(W_h, ws);                  // also zeroes stats
    k_stats<<<NB * NF, 256, 0, stream>>>(query, key, b_h, ws);
    k_attn<<<NB * NF, 256, 0, stream>>>(key, alpha, W_o, b_o, seqn, ws, out);
}

// Round 3
// 209.530 us; speedup vs baseline: 1.0590x; 1.0590x over previous
//
#include <hip/hip_runtime.h>
#include <math.h>

#define NB 256
#define NF 8
#define NS 200
#define ND 64
#define NH 36
#define MT 13              // 13 m-tiles of 16 rows cover 208 >= 200
#define EPSV 1e-3f

// ws float-offset layout:
#define WS_SUM 0                          // [0,288)    per-(f,h) sum
#define WS_SQ  288                        // [288,576)  per-(f,h) sumsq
#define WS_QT  1152                       // 2048*48 floats: qt[b,f,h] (h padded to 48)
#define WS_WK  (1152 + 2048 * 48)         // bf16 WkT[f][h(48)][d(64)] = (W1-W3)^T

typedef __attribute__((ext_vector_type(8))) short short8;
typedef __attribute__((ext_vector_type(4))) float f32x4;

__device__ __forceinline__ unsigned short f32_to_bf16(float x) {
    unsigned u = __float_as_uint(x);
    unsigned r = u + 0x7FFFu + ((u >> 16) & 1u);   // round-to-nearest-even
    return (unsigned short)(r >> 16);
}
__device__ __forceinline__ float bf16_to_f32(unsigned short h) {
    return __uint_as_float(((unsigned)h) << 16);
}
__device__ __forceinline__ short8 cvt8(float4 a, float4 b) {
    short8 r;
    r[0] = (short)f32_to_bf16(a.x); r[1] = (short)f32_to_bf16(a.y);
    r[2] = (short)f32_to_bf16(a.z); r[3] = (short)f32_to_bf16(a.w);
    r[4] = (short)f32_to_bf16(b.x); r[5] = (short)f32_to_bf16(b.y);
    r[6] = (short)f32_to_bf16(b.z); r[7] = (short)f32_to_bf16(b.w);
    return r;
}

// blocks 0..7: WkT bf16 per f. block 8: zero stats. blocks 9..264: qt[b] for b=blk-9.
__global__ __launch_bounds__(256) void k_prep(
    const float* __restrict__ query, const float* __restrict__ W_h,
    const float* __restrict__ b_h, float* __restrict__ ws)
{
    const int blk = blockIdx.x, tid = threadIdx.x;
    if (blk < NF) {
        const int f = blk;
        const float* Wf = W_h + (size_t)f * (3 * ND * NH);
        unsigned short* wk = (unsigned short*)(ws + WS_WK) + f * (48 * ND);
        for (int i = tid; i < 48 * ND; i += 256) {
            int h = i >> 6, d = i & 63;
            float v = (h < NH) ? (Wf[d * NH + h] - Wf[(2 * ND + d) * NH + h]) : 0.f;
            wk[h * ND + d] = f32_to_bf16(v);
        }
    } else if (blk == NF) {
        for (int i = tid; i < 576; i += 256) ws[i] = 0.f;
    } else {
        const int b = blk - NF - 1;
        __shared__ float qs[NF * ND];
        for (int i = tid; i < NF * ND; i += 256)
            qs[i] = query[(size_t)b * NF * ND + i];
        __syncthreads();
        for (int i = tid; i < NF * 48; i += 256) {
            int f = i / 48, h = i - f * 48;
            float acc = 0.f;
            if (h < NH) {
                const float* Wf = W_h + (size_t)f * (3 * ND * NH);
                acc = b_h[f * NH + h];
                for (int d = 0; d < ND; ++d)
                    acc += qs[f * ND + d] * (Wf[(ND + d) * NH + h] + Wf[(2 * ND + d) * NH + h]);
            }
            ws[WS_QT + (size_t)(b * NF + f) * 48 + h] = acc;
        }
    }
}

__global__ __launch_bounds__(256, 3) void k_stats(
    const float* __restrict__ key, float* __restrict__ ws)
{
    const int blk = blockIdx.x;           // = b*NF + f
    const int f = blk & (NF - 1);
    const int tid = threadIdx.x;
    const int lane = tid & 63;
    const int wv = tid >> 6;
    const int col = lane & 15;
    const int quad = lane >> 4;

    __shared__ float sumP[48], sqP[48];
    if (tid < 48) { sumP[tid] = 0.f; sqP[tid] = 0.f; }
    __syncthreads();

    const float* kbase = key + (size_t)blk * (NS * ND);
    const unsigned short* wk = (const unsigned short*)(ws + WS_WK) + f * (48 * ND);

    // batch all key loads for this wave first: 16 float4 in flight (4 KB/wave)
    float4 pf[4][4];
    #pragma unroll
    for (int t = 0; t < 4; ++t) {
        const int mt = wv + 4 * t;
        if (mt < MT) {
            const int s = 16 * mt + col;
            const float4* p = (const float4*)(kbase + (size_t)(s < NS ? s : NS - 1) * ND + quad * 8);
            pf[t][0] = p[0]; pf[t][1] = p[1];    // d = quad*8 .. +7
            pf[t][2] = p[8]; pf[t][3] = p[9];    // d = 32+quad*8 .. +7
        }
    }

    short8 bfr[3][2];
    float qv[3];
    #pragma unroll
    for (int nt = 0; nt < 3; ++nt) {
        #pragma unroll
        for (int ks = 0; ks < 2; ++ks)
            bfr[nt][ks] = *(const short8*)&wk[(nt * 16 + col) * ND + ks * 32 + quad * 8];
        qv[nt] = ws[WS_QT + (size_t)blk * 48 + nt * 16 + col];
    }

    float s_sum[3] = {0.f, 0.f, 0.f}, s_sq[3] = {0.f, 0.f, 0.f};
    #pragma unroll
    for (int t = 0; t < 4; ++t) {
        const int mt = wv + 4 * t;
        if (mt < MT) {
            short8 ah0 = cvt8(pf[t][0], pf[t][1]);
            short8 ah1 = cvt8(pf[t][2], pf[t][3]);
            #pragma unroll
            for (int nt = 0; nt < 3; ++nt) {
                f32x4 acc = {qv[nt], qv[nt], qv[nt], qv[nt]};
                acc = __builtin_amdgcn_mfma_f32_16x16x32_bf16(ah0, bfr[nt][0], acc, 0, 0, 0);
                acc = __builtin_amdgcn_mfma_f32_16x16x32_bf16(ah1, bfr[nt][1], acc, 0, 0, 0);
                #pragma unroll
                for (int r = 0; r < 4; ++r) {
                    int srow = 16 * mt + quad * 4 + r;
                    if (srow < NS) { float v = acc[r]; s_sum[nt] += v; s_sq[nt] += v * v; }
                }
            }
        }
    }
    #pragma unroll
    for (int nt = 0; nt < 3; ++nt) {
        float sv = s_sum[nt], qq = s_sq[nt];
        sv += __shfl_xor(sv, 16, 64); sv += __shfl_xor(sv, 32, 64);
        qq += __shfl_xor(qq, 16, 64); qq += __shfl_xor(qq, 32, 64);
        if (quad == 0) {
            atomicAdd(&sumP[nt * 16 + col], sv);
            atomicAdd(&sqP[nt * 16 + col], qq);
        }
    }
    __syncthreads();
    if (tid < NH) {
        atomicAdd(&ws[WS_SUM + f * NH + tid], sumP[tid]);
        atomicAdd(&ws[WS_SQ + f * NH + tid], sqP[tid]);
    }
}

__global__ __launch_bounds__(256, 3) void k_attn(
    const float* __restrict__ key, const float* __restrict__ alpha,
    const float* __restrict__ W_o, const float* __restrict__ b_o,
    const int* __restrict__ seqn, const float* __restrict__ ws,
    float* __restrict__ out)
{
    const int blk = blockIdx.x;           // = b*NF + f
    const int f = blk & (NF - 1);
    const int tid = threadIdx.x;
    const int lane = tid & 63;
    const int wv = tid >> 6;
    const int col = lane & 15;
    const int quad = lane >> 4;

    __shared__ float sw[208];             // scores, then softmax weights
    __shared__ float redM[4], redS[4];
    __shared__ float pout[4][64];

    const float* kbase = key + (size_t)blk * (NS * ND);
    const unsigned short* wk = (const unsigned short*)(ws + WS_WK) + f * (48 * ND);
    const float inv_n = 1.f / (float)(NB * NS);

    // batch all key loads for this wave, then convert to retained bf16 fragments
    short8 kah[4][2];
    {
        float4 pf[4][4];
        const float4 z4 = {0.f, 0.f, 0.f, 0.f};
        pf[3][0] = z4; pf[3][1] = z4; pf[3][2] = z4; pf[3][3] = z4;  // mt>=MT guard
        #pragma unroll
        for (int t = 0; t < 4; ++t) {
            const int mt = wv + 4 * t;
            if (mt < MT) {
                const int s = 16 * mt + col;
                const float4* p = (const float4*)(kbase + (size_t)(s < NS ? s : NS - 1) * ND + quad * 8);
                pf[t][0] = p[0]; pf[t][1] = p[1];
                pf[t][2] = p[8]; pf[t][3] = p[9];
            }
        }
        #pragma unroll
        for (int t = 0; t < 4; ++t) {
            kah[t][0] = cvt8(pf[t][0], pf[t][1]);
            kah[t][1] = cvt8(pf[t][2], pf[t][3]);
        }
    }

    short8 bfr[3][2];
    float qv[3], mn[3], iv[3], wo[3];
    #pragma unroll
    for (int nt = 0; nt < 3; ++nt) {
        #pragma unroll
        for (int ks = 0; ks < 2; ++ks)
            bfr[nt][ks] = *(const short8*)&wk[(nt * 16 + col) * ND + ks * 32 + quad * 8];
        const int hh = nt * 16 + col;
        const bool hv = hh < NH;
        const int hc = hv ? hh : 0;
        qv[nt] = ws[WS_QT + (size_t)blk * 48 + hh];
        const float sm = ws[WS_SUM + f * NH + hc];
        const float sq = ws[WS_SQ + f * NH + hc];
        const float m = sm * inv_n;
        mn[nt] = m;
        iv[nt] = rsqrtf(fmaxf(sq * inv_n - m * m, 0.f) + EPSV);
        wo[nt] = hv ? W_o[f * NH + hh] : 0.f;
    }
    const float alf = alpha[f];
    const float bo = b_o[f];
    const int sq_n = seqn[blk];

    // score phase: register-only MFMA + gated sum
    #pragma unroll
    for (int t = 0; t < 4; ++t) {
        const int mt = wv + 4 * t;
        if (mt < MT) {
            float part[4] = {0.f, 0.f, 0.f, 0.f};
            #pragma unroll
            for (int nt = 0; nt < 3; ++nt) {
                f32x4 acc = {qv[nt], qv[nt], qv[nt], qv[nt]};
                acc = __builtin_amdgcn_mfma_f32_16x16x32_bf16(kah[t][0], bfr[nt][0], acc, 0, 0, 0);
                acc = __builtin_amdgcn_mfma_f32_16x16x32_bf16(kah[t][1], bfr[nt][1], acc, 0, 0, 0);
                #pragma unroll
                for (int r = 0; r < 4; ++r) {
                    const float h = acc[r];
                    const float pg = 1.f / (1.f + __expf(-(h - mn[nt]) * iv[nt]));
                    part[r] += (alf + (1.f - alf) * pg) * h * wo[nt];
                }
            }
            #pragma unroll
            for (int r = 0; r < 4; ++r) {
                float v = part[r];
                v += __shfl_xor(v, 1, 64);
                v += __shfl_xor(v, 2, 64);
                v += __shfl_xor(v, 4, 64);
                v += __shfl_xor(v, 8, 64);
                const int srow = 16 * mt + quad * 4 + r;
                if (col == 0 && srow < NS) sw[srow] = v + bo;
            }
        }
    }
    __syncthreads();

    // softmax over s
    const bool valid = (tid < 208) && (tid < sq_n);
    const float sc = valid ? sw[tid] : -1e30f;
    float m = sc;
    m = fmaxf(m, __shfl_xor(m, 1, 64));  m = fmaxf(m, __shfl_xor(m, 2, 64));
    m = fmaxf(m, __shfl_xor(m, 4, 64));  m = fmaxf(m, __shfl_xor(m, 8, 64));
    m = fmaxf(m, __shfl_xor(m, 16, 64)); m = fmaxf(m, __shfl_xor(m, 32, 64));
    if (lane == 0) redM[wv] = m;
    __syncthreads();
    const float maxv = fmaxf(fmaxf(redM[0], redM[1]), fmaxf(redM[2], redM[3]));
    const float e = valid ? __expf(sc - maxv) : 0.f;
    float l = e;
    l += __shfl_xor(l, 1, 64);  l += __shfl_xor(l, 2, 64);
    l += __shfl_xor(l, 4, 64);  l += __shfl_xor(l, 8, 64);
    l += __shfl_xor(l, 16, 64); l += __shfl_xor(l, 32, 64);
    if (lane == 0) redS[wv] = l;
    __syncthreads();
    const float isum = 1.f / (redS[0] + redS[1] + redS[2] + redS[3]);
    if (tid < 208) sw[tid] = e * isum;
    __syncthreads();

    // out = attn @ key, from retained bf16 fragments
    float po0[8] = {0,0,0,0,0,0,0,0}, po1[8] = {0,0,0,0,0,0,0,0};
    #pragma unroll
    for (int t = 0; t < 4; ++t) {
        const int mt = wv + 4 * t;
        if (mt < MT) {
            const float w = sw[16 * mt + col];   // rows >= NS carry weight 0
            #pragma unroll
            for (int j = 0; j < 8; ++j) {
                po0[j] += w * bf16_to_f32((unsigned short)kah[t][0][j]);
                po1[j] += w * bf16_to_f32((unsigned short)kah[t][1][j]);
            }
        }
    }
    #pragma unroll
    for (int off = 1; off <= 8; off <<= 1) {
        #pragma unroll
        for (int j = 0; j < 8; ++j) {
            po0[j] += __shfl_xor(po0[j], off, 64);
            po1[j] += __shfl_xor(po1[j], off, 64);
        }
    }
    if (col == 0) {
        #pragma unroll
        for (int j = 0; j < 8; ++j) {
            pout[wv][quad * 8 + j] = po0[j];
            pout[wv][32 + quad * 8 + j] = po1[j];
        }
    }
    __syncthreads();
    if (tid < 64)
        out[(size_t)blk * ND + tid] =
            pout[0][tid] + pout[1][tid] + pout[2][tid] + pout[3][tid];
}

extern "C" void kernel_launch(void* const* d_in, const int* in_sizes, int n_in,
                              void* d_out, int out_size, void* d_ws, size_t ws_size,
                              hipStream_t stream) {
    const float* query = (const float*)d_in[0];
    const float* key   = (const float*)d_in[1];
    const float* W_h   = (const float*)d_in[2];
    const float* b_h   = (const float*)d_in[3];
    const float* alpha = (const float*)d_in[4];
    const float* W_o   = (const float*)d_in[5];
    const float* b_o   = (const float*)d_in[6];
    const int*   seqn  = (const int*)d_in[7];
    float* out = (float*)d_out;
    float* ws  = (float*)d_ws;

    k_prep<<<NB + NF + 1, 256, 0, stream>>>(query, W_h, b_h, ws);  // wk + zero-stats + qt
    k_stats<<<NB * NF, 256, 0, stream>>>(key, ws);
    k_attn<<<NB * NF, 256, 0, stream>>>(key, alpha, W_o, b_o, seqn, ws, out);
}